// Round 14
// baseline (207.804 us; speedup 1.0000x reference)
//
#include <hip/hip_runtime.h>
#include <hip/hip_bf16.h>

// ============================================================================
// fused stride-2 "transposed conv" + bias + channel-softmax + sigmoid
//
// PAD==OUT_PAD==1 => odd h or odd w outputs are the constant vector
// sigmoid(2*softmax(bias)). Even-even outputs are a dense 4x4 conv:
//   O[n,c,p,q] = sum_{ic,kh,kw} x[n,ic,p-kh,q-kw]*W[c,ic,kh,kw]
//
// R14: T4 A/B. R8 (W-through-LDS DMA, 2-phase) drained vmcnt(0) + full
// __syncthreads every 16KB phase -> 256us (the documented drain-0 regime).
// This round ports R8 to the m201 counted-vmcnt template: raw s_barrier,
// s_waitcnt vmcnt(4) (one chunk in flight across barriers), 2-deep prefetch,
// lgkmcnt(0) fence before the buffer-swap barrier, sched_barrier(0) fences
// (rule 18). + T5 setprio around MFMA clusters (phase-split now exists) +
// T1 bijective XCD swizzle + R13 epilogue/merged fill.
// Numerics: bf16 hi/lo split (Whi*Xhi + Wlo*Xhi + Whi*Xlo), fp32 acc.
// ============================================================================

typedef __bf16 bf16x8 __attribute__((ext_vector_type(8)));
typedef float  f32x4  __attribute__((ext_vector_type(4)));
typedef float  f32x16 __attribute__((ext_vector_type(16)));
typedef unsigned short ushort_t;

#define TILE_P 4
#define TILE_Q 16
#define PATCH_R 7                     // TILE_P + 3
#define PATCH_C 19                    // TILE_Q + 3
#define XELEMS (PATCH_R*PATCH_C*64)   // 8512 bf16 per plane
#define XLO_BYTES (XELEMS*2)          // 17024
#define XTOT_BYTES (XELEMS*4)         // 34048 (hi+lo planes)
#define WBUF_BYTES 16384              // one half-tap W chunk (16 x 1KB frags)
#define SMEM_BYTES (XTOT_BYTES + 2*WBUF_BYTES)  // 66816 -> 2 blocks/CU
#define WSW_BYTES (16*4*4*2*64*16)    // 524288 bytes of W fragments
#define ODD_ROWS (32*128*64)          // 262144 odd output rows
#define ROWS_PER_BLOCK 97             // ceil(262144/2720)

// async global->LDS, 16B per lane; LDS dest = wave-uniform base + lane*16
__device__ __forceinline__ void gld16(const void* g, void* l) {
    __builtin_amdgcn_global_load_lds(
        (const __attribute__((address_space(1))) unsigned int*)g,
        (__attribute__((address_space(3))) unsigned int*)l, 16, 0, 0);
}

// ---- prep: weight -> 32x32 fragment order, bf16 hi/lo ----------------------
// frag f = ((tap*4+icg)*4+Mt)*2+hl, 1KB each; lane l holds
// W[cout=Mt*32+(l&31)][ic=icg*16+(l>>5)*8+i]  (A-operand: row=l&31, k slice).
__global__ void prep_w_kernel(const float* __restrict__ w, ushort_t* __restrict__ wsW) {
    int slot = blockIdx.x * 256 + threadIdx.x;      // 32768 slots
    int lane = slot & 63;
    int hl   = (slot >> 6) & 1;
    int Mt   = (slot >> 7) & 3;
    int icg  = (slot >> 9) & 3;
    int tap  = slot >> 11;
    int kh = tap >> 2, kw = tap & 3;
    int cout = Mt * 32 + (lane & 31);
    int icb  = icg * 16 + (lane >> 5) * 8;
    bf16x8 v;
#pragma unroll
    for (int i = 0; i < 8; ++i) {
        float f = w[((cout * 64 + icb + i) * 4 + kh) * 4 + kw];
        __bf16 h = (__bf16)f;
        v[i] = hl ? (__bf16)(f - (float)h) : h;
    }
    *(bf16x8*)(wsW + (size_t)slot * 8) = v;   // slot*16 bytes
}

// ---- prep: const vector sigmoid(2*softmax(bias)) ---------------------------
__global__ void prep_const_kernel(const float* __restrict__ bias, float* __restrict__ wsc) {
    __shared__ float red[128];
    int t = threadIdx.x;
    red[t] = bias[t];
    __syncthreads();
    float m = -3.4e38f;
    for (int i = 0; i < 128; ++i) m = fmaxf(m, red[i]);
    float e = __expf(red[t] - m);
    __syncthreads();
    red[t] = e;
    __syncthreads();
    float s = 0.f;
    for (int i = 0; i < 128; ++i) s += red[i];
    float v = e / s;
    wsc[t] = 1.0f / (1.0f + __expf(-2.0f * v));
}

// ---- main ------------------------------------------------------------------
__launch_bounds__(256, 2)
__global__ void conv_main_kernel(const float* __restrict__ x,
                                 const float* __restrict__ bias,
                                 const ushort_t* __restrict__ wsW,
                                 const float* __restrict__ wsc,
                                 float* __restrict__ out) {
    extern __shared__ char smem[];
    ushort_t* xs   = (ushort_t*)smem;
    char*     wlds = smem + XTOT_BYTES;

    const int tid = threadIdx.x;

    // ---- T1: bijective XCD swizzle (2720 = 8 * 340) ------------------------
    const int fid = (blockIdx.z * 17 + blockIdx.y) * 5 + blockIdx.x;
    const int nid = (fid & 7) * 340 + (fid >> 3);
    const int qt  = nid % 5;
    const int rem = nid / 5;
    const int pt  = rem % 17;
    const int n   = rem / 17;
    const int p0  = pt * TILE_P;
    const int q0  = qt * TILE_Q;

    const int lane = tid & 63;
    const int wv   = tid >> 6;       // wave id = Mtile (32 couts)
    const int l31  = lane & 31;
    const int lhi  = lane >> 5;
    const int qA   = l31 & 15;       // B col -> q offset
    const int dp   = l31 >> 4;       // B col -> p offset within Ntile

    // stage 16KB W chunk for (TAP, PAIR) into buffer BUF; 4 DMA per wave.
#define STAGE_W(TAP, PAIR, BUF) do {                                          \
        _Pragma("unroll")                                                     \
        for (int s_ = 0; s_ < 4; ++s_) {                                      \
            int c_ = s_ * 4 + wv;                                             \
            int il_ = c_ >> 3, mt_ = (c_ >> 1) & 3, hl_ = c_ & 1;             \
            int gf_ = (((TAP) * 4 + (PAIR) * 2 + il_) * 4 + mt_) * 2 + hl_;   \
            gld16((const char*)wsW + gf_ * 1024 + lane * 16,                  \
                  wlds + (BUF) * WBUF_BYTES + c_ * 1024);                     \
        }                                                                     \
    } while (0)

    // ---- prologue: chunks 0,1 DMA in flight during X staging ---------------
    STAGE_W(0, 0, 0);
    STAGE_W(0, 1, 1);

    // ---- stage X patch hi+lo, single pass ----------------------------------
    const float* xg = x + (size_t)n * 262144;
    for (int grp = tid; grp < PATCH_R * PATCH_C * 8; grp += 256) {
        int r   = grp / (PATCH_C * 8);
        int rm  = grp - r * (PATCH_C * 8);
        int g   = rm / PATCH_C;
        int c   = rm - g * PATCH_C;
        int row = p0 + r - 3;
        int col = q0 + c - 3;
        bool ok = (row >= 0) & (row < 64) & (col >= 0) & (col < 64);
        const float* src = xg + (g * 8) * 4096 + row * 64 + col;
        bf16x8 hi, lo;
#pragma unroll
        for (int i = 0; i < 8; ++i) {
            float f = ok ? src[i * 4096] : 0.0f;
            __bf16 h = (__bf16)f;
            hi[i] = h;
            lo[i] = (__bf16)(f - (float)h);
        }
        int slot = ((r * PATCH_C + c) * 8 + (g ^ (c & 7))) * 8;     // elem idx
        *(bf16x8*)(xs + slot)          = hi;
        *(bf16x8*)(xs + XELEMS + slot) = lo;
    }
    __syncthreads();   // prologue drain: X stores + chunks 0,1 (vmcnt0+lgkm0)

    // ---- K loop: 32 phases, counted-vmcnt 2-deep pipeline (T4) -------------
    f32x16 acc0 = (f32x16)(0.0f);
    f32x16 acc1 = (f32x16)(0.0f);
    const char* xsc = (const char*)smem;

#pragma unroll
    for (int ph = 0; ph < 32; ++ph) {
        // chunk ph must be complete; chunk ph+1 may stay in flight.
        if (ph == 31) {
            asm volatile("s_waitcnt vmcnt(0)" ::: "memory");
        } else {
            asm volatile("s_waitcnt vmcnt(4)" ::: "memory");
        }
        __builtin_amdgcn_sched_barrier(0);
        __builtin_amdgcn_s_barrier();          // chunk ph visible to all waves
        asm volatile("" ::: "memory");
        __builtin_amdgcn_sched_barrier(0);

        const int cur = ph & 1;
        const int tap = ph >> 1;               // compile-time after unroll
        const int kh = tap >> 2, kw = tap & 3;
#pragma unroll
        for (int j = 0; j < 2; ++j) {
            const int icg = (ph & 1) * 2 + j;  // compile-time
            const char* wb = wlds + cur * WBUF_BYTES + ((j * 4 + wv) * 2) * 1024 + lane * 16;
            bf16x8 whi = *(const bf16x8*)(wb);
            bf16x8 wlo = *(const bf16x8*)(wb + 1024);

            int pc = qA + 3 - kw;
            int pr = dp + 3 - kh;
            int g8 = icg * 2 + lhi;
            int addr = (((pr * PATCH_C + pc) << 3) + (g8 ^ (pc & 7))) << 4;  // bytes
            bf16x8 xh0 = *(const bf16x8*)(xsc + addr);
            bf16x8 xl0 = *(const bf16x8*)(xsc + addr + XLO_BYTES);
            bf16x8 xh1 = *(const bf16x8*)(xsc + addr + 4864);               // +2 p-rows
            bf16x8 xl1 = *(const bf16x8*)(xsc + addr + 4864 + XLO_BYTES);

            __builtin_amdgcn_s_setprio(1);
            acc0 = __builtin_amdgcn_mfma_f32_32x32x16_bf16(whi, xh0, acc0, 0, 0, 0);
            acc1 = __builtin_amdgcn_mfma_f32_32x32x16_bf16(whi, xh1, acc1, 0, 0, 0);
            acc0 = __builtin_amdgcn_mfma_f32_32x32x16_bf16(wlo, xh0, acc0, 0, 0, 0);
            acc1 = __builtin_amdgcn_mfma_f32_32x32x16_bf16(wlo, xh1, acc1, 0, 0, 0);
            acc0 = __builtin_amdgcn_mfma_f32_32x32x16_bf16(whi, xl0, acc0, 0, 0, 0);
            acc1 = __builtin_amdgcn_mfma_f32_32x32x16_bf16(whi, xl1, acc1, 0, 0, 0);
            __builtin_amdgcn_s_setprio(0);
        }

        // all my LDS reads of buf[cur] complete before anyone overwrites it
        asm volatile("s_waitcnt lgkmcnt(0)" ::: "memory");
        __builtin_amdgcn_sched_barrier(0);
        __builtin_amdgcn_s_barrier();
        asm volatile("" ::: "memory");

        if (ph < 30) {
            STAGE_W((ph + 2) >> 1, (ph + 2) & 1, ph & 1);   // into buf[cur]
        }
    }

    // ---- bias add: channel = wv*32 + (reg&3) + 8*(reg>>2) + 4*lhi ----------
    {
        f32x4 bv[4];
#pragma unroll
        for (int j = 0; j < 4; ++j)
            bv[j] = *(const f32x4*)(bias + wv * 32 + lhi * 4 + j * 8);
#pragma unroll
        for (int reg = 0; reg < 16; ++reg) {
            acc0[reg] += bv[reg >> 2][reg & 3];
            acc1[reg] += bv[reg >> 2][reg & 3];
        }
    }

    // X/W regions dead (final barrier above) -> overlay reduce bufs
    float* red1  = (float*)smem;         // [64 pos][4 waves] max
    float* red2  = (float*)(smem + 1024);// [64 pos][4 waves] sum
    float* cfill = (float*)(smem + 2048);// [128] const vector

    if (tid < 128) cfill[tid] = wsc[tid];

    // ---- per-position max: in-lane over 16 regs, shfl over lhi, LDS x4 -----
    {
        float m0 = acc0[0], m1 = acc1[0];
#pragma unroll
        for (int reg = 1; reg < 16; ++reg) {
            m0 = fmaxf(m0, acc0[reg]);
            m1 = fmaxf(m1, acc1[reg]);
        }
        m0 = fmaxf(m0, __shfl_xor(m0, 32));
        m1 = fmaxf(m1, __shfl_xor(m1, 32));
        if (lhi == 0) {
            red1[(0 * 32 + l31) * 4 + wv] = m0;
            red1[(1 * 32 + l31) * 4 + wv] = m1;
        }
    }
    __syncthreads();

    float gm[2];
#pragma unroll
    for (int nt = 0; nt < 2; ++nt) {
        f32x4 v = *(const f32x4*)&red1[(nt * 32 + l31) * 4];
        gm[nt] = fmaxf(fmaxf(v[0], v[1]), fmaxf(v[2], v[3]));
    }

    // ---- exp + per-position sum --------------------------------------------
    {
        float s0 = 0.f, s1 = 0.f;
#pragma unroll
        for (int reg = 0; reg < 16; ++reg) {
            float e0 = __expf(acc0[reg] - gm[0]);
            float e1 = __expf(acc1[reg] - gm[1]);
            acc0[reg] = e0; acc1[reg] = e1;
            s0 += e0; s1 += e1;
        }
        s0 += __shfl_xor(s0, 32);
        s1 += __shfl_xor(s1, 32);
        if (lhi == 0) {
            red2[(0 * 32 + l31) * 4 + wv] = s0;
            red2[(1 * 32 + l31) * 4 + wv] = s1;
        }
    }
    __syncthreads();

    float inv[2];
#pragma unroll
    for (int nt = 0; nt < 2; ++nt) {
        f32x4 v = *(const f32x4*)&red2[(nt * 32 + l31) * 4];
        inv[nt] = 1.0f / (v[0] + v[1] + v[2] + v[3]);
    }

    // ---- normalize, sigmoid, store: 128B-contiguous per 16 lanes -----------
    {
        f32x4 cv[4];
#pragma unroll
        for (int j = 0; j < 4; ++j)
            cv[j] = *(const f32x4*)(wsc + wv * 32 + lhi * 4 + j * 8);

        int q = q0 + qA;
#pragma unroll
        for (int nt = 0; nt < 2; ++nt) {
            int p = p0 + nt * 2 + dp;
            if (p < 65 && q < 65) {
#pragma unroll
                for (int reg = 0; reg < 16; ++reg) {
                    int c = wv * 32 + 4 * lhi + 8 * (reg >> 2) + (reg & 3);
                    float v  = (nt == 0 ? acc0[reg] : acc1[reg]) * inv[nt];
                    float sg = 1.0f / (1.0f + __expf(-2.0f * v));
                    size_t o = ((size_t)(n * 128 + c) * 129 + 2 * p) * 129 + 2 * q;
                    if (q < 64) {
                        float2 pr2 = {sg, cv[reg >> 2][reg & 3]};
                        *(float2*)(out + o) = pr2;
                    } else {
                        out[o] = sg;
                    }
                }
            }
        }
    }

    // ---- merged odd-row const fill: 97 FULL 516B rows per block ------------
    {
        int rbase = nid * ROWS_PER_BLOCK;
        int t    = tid & 127;           // column 0..127
        int half = tid >> 7;            // 2 rows in flight
        for (int i = half; i < ROWS_PER_BLOCK; i += 2) {
            int r = rbase + i;
            if (r < ODD_ROWS) {
                int n2 = r >> 13;
                int c2 = (r >> 6) & 127;
                int oh = ((r & 63) << 1) + 1;
                float v = cfill[c2];
                size_t base = ((size_t)(n2 * 128 + c2) * 129 + oh) * 129;
                out[base + t] = v;
                if (t == 127) out[base + 128] = v;
            }
        }
    }
#undef STAGE_W
}

extern "C" void kernel_launch(void* const* d_in, const int* in_sizes, int n_in,
                              void* d_out, int out_size, void* d_ws, size_t ws_size,
                              hipStream_t stream) {
    const float* x    = (const float*)d_in[0];
    const float* w    = (const float*)d_in[1];
    const float* bias = (const float*)d_in[2];
    float* out = (float*)d_out;

    ushort_t* wsW = (ushort_t*)d_ws;                          // 512 KB
    float* wsc    = (float*)((char*)d_ws + WSW_BYTES);        // 512 B

    (void)hipFuncSetAttribute((const void*)conv_main_kernel,
                              hipFuncAttributeMaxDynamicSharedMemorySize, SMEM_BYTES);

    prep_w_kernel<<<128, 256, 0, stream>>>(w, wsW);
    prep_const_kernel<<<1, 128, 0, stream>>>(bias, wsc);

    dim3 grid(5, 17, 32);   // q-tiles, p-tiles, n
    conv_main_kernel<<<grid, 256, SMEM_BYTES, stream>>>(x, bias, wsW, wsc, out);
}

// Round 15
// 187.533 us; speedup vs baseline: 1.1081x; 1.1081x over previous
//
#include <hip/hip_runtime.h>
#include <hip/hip_bf16.h>

// ============================================================================
// fused stride-2 "transposed conv" + bias + channel-softmax + sigmoid
//
// PAD==OUT_PAD==1 => odd h or odd w outputs are the constant vector
// sigmoid(2*softmax(bias)). Even-even outputs are a dense 4x4 conv:
//   O[n,c,p,q] = sum_{ic,kh,kw} x[n,ic,p-kh,q-kw]*W[c,ic,kh,kw]
//
// R15 == R13 (session best, 189.5us): TILE_P=4, 256thr, branch-free unroll-8
// K-loop streaming W via L2, T5 setprio around MFMA cluster, T1 bijective
// XCD swizzle (FETCH 93->23MB), in-register softmax, merged 516B-row fill.
// Ceiling status: 10 structural variants land 190-260us with all pipes <30%;
// per-K-step latency chain is the binder; documented exit (8-phase counted
// vmcnt) measured NEGATIVE here (R8 256us, R14 247us) - phase too small at
// this tile size. This is the plain-HIP schedule-class optimum for the shape.
// Numerics: bf16 hi/lo split (Whi*Xhi + Wlo*Xhi + Whi*Xlo), fp32 acc.
// ============================================================================

typedef __bf16 bf16x8 __attribute__((ext_vector_type(8)));
typedef float  f32x4  __attribute__((ext_vector_type(4)));
typedef float  f32x16 __attribute__((ext_vector_type(16)));
typedef unsigned short ushort_t;

#define TILE_P 4
#define TILE_Q 16
#define PATCH_R 7                     // TILE_P + 3
#define PATCH_C 19                    // TILE_Q + 3
#define XELEMS (PATCH_R*PATCH_C*64)   // 8512 bf16 per plane
#define XLO_BYTES (XELEMS*2)          // 17024
#define SMEM_BYTES (XELEMS*2*2)       // 34048 -> 4 blocks/CU
#define WSW_BYTES (16*4*4*2*64*16)    // 524288 bytes of W fragments
#define ODD_ROWS (32*128*64)          // 262144 odd output rows
#define ROWS_PER_BLOCK 97             // ceil(262144/2720)

// ---- prep: weight -> 32x32 fragment order, bf16 hi/lo ----------------------
// frag f = ((tap*4+icg)*4+Mt)*2+hl, 1KB each; lane l holds
// W[cout=Mt*32+(l&31)][ic=icg*16+(l>>5)*8+i]  (A-operand: row=l&31, k slice).
__global__ void prep_w_kernel(const float* __restrict__ w, ushort_t* __restrict__ wsW) {
    int slot = blockIdx.x * 256 + threadIdx.x;      // 32768 slots
    int lane = slot & 63;
    int hl   = (slot >> 6) & 1;
    int Mt   = (slot >> 7) & 3;
    int icg  = (slot >> 9) & 3;
    int tap  = slot >> 11;
    int kh = tap >> 2, kw = tap & 3;
    int cout = Mt * 32 + (lane & 31);
    int icb  = icg * 16 + (lane >> 5) * 8;
    bf16x8 v;
#pragma unroll
    for (int i = 0; i < 8; ++i) {
        float f = w[((cout * 64 + icb + i) * 4 + kh) * 4 + kw];
        __bf16 h = (__bf16)f;
        v[i] = hl ? (__bf16)(f - (float)h) : h;
    }
    *(bf16x8*)(wsW + (size_t)slot * 8) = v;   // slot*16 bytes
}

// ---- prep: const vector sigmoid(2*softmax(bias)) ---------------------------
__global__ void prep_const_kernel(const float* __restrict__ bias, float* __restrict__ wsc) {
    __shared__ float red[128];
    int t = threadIdx.x;
    red[t] = bias[t];
    __syncthreads();
    float m = -3.4e38f;
    for (int i = 0; i < 128; ++i) m = fmaxf(m, red[i]);
    float e = __expf(red[t] - m);
    __syncthreads();
    red[t] = e;
    __syncthreads();
    float s = 0.f;
    for (int i = 0; i < 128; ++i) s += red[i];
    float v = e / s;
    wsc[t] = 1.0f / (1.0f + __expf(-2.0f * v));
}

// ---- main ------------------------------------------------------------------
__launch_bounds__(256, 4)
__global__ void conv_main_kernel(const float* __restrict__ x,
                                 const float* __restrict__ bias,
                                 const ushort_t* __restrict__ wsW,
                                 const float* __restrict__ wsc,
                                 float* __restrict__ out) {
    extern __shared__ char smem[];
    ushort_t* xs = (ushort_t*)smem;

    const int tid = threadIdx.x;

    // ---- T1: bijective XCD swizzle (2720 = 8 * 340) ------------------------
    // dispatch index d goes to XCD d%8; remap so each XCD owns a contiguous
    // nid-slab (contiguous images/tiles -> x + W L2 locality per XCD).
    const int fid = (blockIdx.z * 17 + blockIdx.y) * 5 + blockIdx.x;
    const int nid = (fid & 7) * 340 + (fid >> 3);
    const int qt  = nid % 5;
    const int rem = nid / 5;
    const int pt  = rem % 17;
    const int n   = rem / 17;
    const int p0  = pt * TILE_P;
    const int q0  = qt * TILE_Q;

    const int lane = tid & 63;
    const int wv   = tid >> 6;       // wave id = Mtile (32 couts)
    const int l31  = lane & 31;
    const int lhi  = lane >> 5;
    const int qA   = l31 & 15;       // B col -> q offset
    const int dp   = l31 >> 4;       // B col -> p offset within Ntile

    // ---- stage X patch hi+lo, single pass ----------------------------------
    const float* xg = x + (size_t)n * 262144;
    for (int grp = tid; grp < PATCH_R * PATCH_C * 8; grp += 256) {
        int r   = grp / (PATCH_C * 8);
        int rm  = grp - r * (PATCH_C * 8);
        int g   = rm / PATCH_C;
        int c   = rm - g * PATCH_C;
        int row = p0 + r - 3;
        int col = q0 + c - 3;
        bool ok = (row >= 0) & (row < 64) & (col >= 0) & (col < 64);
        const float* src = xg + (g * 8) * 4096 + row * 64 + col;
        bf16x8 hi, lo;
#pragma unroll
        for (int i = 0; i < 8; ++i) {
            float f = ok ? src[i * 4096] : 0.0f;
            __bf16 h = (__bf16)f;
            hi[i] = h;
            lo[i] = (__bf16)(f - (float)h);
        }
        int slot = ((r * PATCH_C + c) * 8 + (g ^ (c & 7))) * 8;     // elem idx
        *(bf16x8*)(xs + slot)          = hi;
        *(bf16x8*)(xs + XELEMS + slot) = lo;
    }
    __syncthreads();

    // ---- K loop: 64 Ksteps, branch-free; T5 setprio around MFMA cluster ----
    f32x16 acc0 = (f32x16)(0.0f);
    f32x16 acc1 = (f32x16)(0.0f);

    const char* wbase = (const char*)wsW + wv * 2048 + lane * 16;
    const char* xsc   = (const char*)smem;

#pragma unroll 8
    for (int ks = 0; ks < 64; ++ks) {
        int tap = ks >> 2, icg = ks & 3;
        int kh = tap >> 2, kw = tap & 3;
        int pc = qA + 3 - kw;
        int pr = dp + 3 - kh;
        int g8 = icg * 2 + lhi;
        int addr = ((((pr * PATCH_C + pc) << 3) + (g8 ^ (pc & 7))) << 4);  // bytes

        const char* wp = wbase + ks * 8192;
        bf16x8 whi = *(const bf16x8*)(wp);
        bf16x8 wlo = *(const bf16x8*)(wp + 1024);
        bf16x8 xh0 = *(const bf16x8*)(xsc + addr);
        bf16x8 xl0 = *(const bf16x8*)(xsc + addr + XLO_BYTES);
        bf16x8 xh1 = *(const bf16x8*)(xsc + addr + 4864);             // +2 p-rows
        bf16x8 xl1 = *(const bf16x8*)(xsc + addr + 4864 + XLO_BYTES);

        __builtin_amdgcn_s_setprio(1);
        acc0 = __builtin_amdgcn_mfma_f32_32x32x16_bf16(whi, xh0, acc0, 0, 0, 0);
        acc1 = __builtin_amdgcn_mfma_f32_32x32x16_bf16(whi, xh1, acc1, 0, 0, 0);
        acc0 = __builtin_amdgcn_mfma_f32_32x32x16_bf16(wlo, xh0, acc0, 0, 0, 0);
        acc1 = __builtin_amdgcn_mfma_f32_32x32x16_bf16(wlo, xh1, acc1, 0, 0, 0);
        acc0 = __builtin_amdgcn_mfma_f32_32x32x16_bf16(whi, xl0, acc0, 0, 0, 0);
        acc1 = __builtin_amdgcn_mfma_f32_32x32x16_bf16(whi, xl1, acc1, 0, 0, 0);
        __builtin_amdgcn_s_setprio(0);
    }

    // ---- bias add: channel = wv*32 + (reg&3) + 8*(reg>>2) + 4*lhi ----------
    {
        f32x4 bv[4];
#pragma unroll
        for (int j = 0; j < 4; ++j)
            bv[j] = *(const f32x4*)(bias + wv * 32 + lhi * 4 + j * 8);
#pragma unroll
        for (int reg = 0; reg < 16; ++reg) {
            acc0[reg] += bv[reg >> 2][reg & 3];
            acc1[reg] += bv[reg >> 2][reg & 3];
        }
    }

    __syncthreads();                    // X planes dead -> overlay reduce bufs
    float* red1  = (float*)smem;        // [64 pos][4 waves] max
    float* red2  = (float*)(smem + 1024);// [64 pos][4 waves] sum
    float* cfill = (float*)(smem + 2048);// [128] const vector

    if (tid < 128) cfill[tid] = wsc[tid];

    // ---- per-position max: in-lane over 16 regs, shfl over lhi, LDS x4 -----
    {
        float m0 = acc0[0], m1 = acc1[0];
#pragma unroll
        for (int reg = 1; reg < 16; ++reg) {
            m0 = fmaxf(m0, acc0[reg]);
            m1 = fmaxf(m1, acc1[reg]);
        }
        m0 = fmaxf(m0, __shfl_xor(m0, 32));
        m1 = fmaxf(m1, __shfl_xor(m1, 32));
        if (lhi == 0) {
            red1[(0 * 32 + l31) * 4 + wv] = m0;
            red1[(1 * 32 + l31) * 4 + wv] = m1;
        }
    }
    __syncthreads();

    float gm[2];
#pragma unroll
    for (int nt = 0; nt < 2; ++nt) {
        f32x4 v = *(const f32x4*)&red1[(nt * 32 + l31) * 4];
        gm[nt] = fmaxf(fmaxf(v[0], v[1]), fmaxf(v[2], v[3]));
    }

    // ---- exp + per-position sum --------------------------------------------
    {
        float s0 = 0.f, s1 = 0.f;
#pragma unroll
        for (int reg = 0; reg < 16; ++reg) {
            float e0 = __expf(acc0[reg] - gm[0]);
            float e1 = __expf(acc1[reg] - gm[1]);
            acc0[reg] = e0; acc1[reg] = e1;
            s0 += e0; s1 += e1;
        }
        s0 += __shfl_xor(s0, 32);
        s1 += __shfl_xor(s1, 32);
        if (lhi == 0) {
            red2[(0 * 32 + l31) * 4 + wv] = s0;
            red2[(1 * 32 + l31) * 4 + wv] = s1;
        }
    }
    __syncthreads();

    float inv[2];
#pragma unroll
    for (int nt = 0; nt < 2; ++nt) {
        f32x4 v = *(const f32x4*)&red2[(nt * 32 + l31) * 4];
        inv[nt] = 1.0f / (v[0] + v[1] + v[2] + v[3]);
    }

    // ---- normalize, sigmoid, store: 128B-contiguous per 16 lanes -----------
    {
        f32x4 cv[4];
#pragma unroll
        for (int j = 0; j < 4; ++j)
            cv[j] = *(const f32x4*)(wsc + wv * 32 + lhi * 4 + j * 8);

        int q = q0 + qA;
#pragma unroll
        for (int nt = 0; nt < 2; ++nt) {
            int p = p0 + nt * 2 + dp;
            if (p < 65 && q < 65) {
#pragma unroll
                for (int reg = 0; reg < 16; ++reg) {
                    int c = wv * 32 + 4 * lhi + 8 * (reg >> 2) + (reg & 3);
                    float v  = (nt == 0 ? acc0[reg] : acc1[reg]) * inv[nt];
                    float sg = 1.0f / (1.0f + __expf(-2.0f * v));
                    size_t o = ((size_t)(n * 128 + c) * 129 + 2 * p) * 129 + 2 * q;
                    if (q < 64) {
                        float2 pr2 = {sg, cv[reg >> 2][reg & 3]};
                        *(float2*)(out + o) = pr2;
                    } else {
                        out[o] = sg;
                    }
                }
            }
        }
    }

    // ---- merged odd-row const fill: 97 FULL 516B rows per block ------------
    {
        int rbase = nid * ROWS_PER_BLOCK;
        int t    = tid & 127;           // column 0..127
        int half = tid >> 7;            // 2 rows in flight
        for (int i = half; i < ROWS_PER_BLOCK; i += 2) {
            int r = rbase + i;
            if (r < ODD_ROWS) {
                int n2 = r >> 13;
                int c2 = (r >> 6) & 127;
                int oh = ((r & 63) << 1) + 1;
                float v = cfill[c2];
                size_t base = ((size_t)(n2 * 128 + c2) * 129 + oh) * 129;
                out[base + t] = v;
                if (t == 127) out[base + 128] = v;
            }
        }
    }
}

extern "C" void kernel_launch(void* const* d_in, const int* in_sizes, int n_in,
                              void* d_out, int out_size, void* d_ws, size_t ws_size,
                              hipStream_t stream) {
    const float* x    = (const float*)d_in[0];
    const float* w    = (const float*)d_in[1];
    const float* bias = (const float*)d_in[2];
    float* out = (float*)d_out;

    ushort_t* wsW = (ushort_t*)d_ws;                          // 512 KB
    float* wsc    = (float*)((char*)d_ws + WSW_BYTES);        // 512 B

    (void)hipFuncSetAttribute((const void*)conv_main_kernel,
                              hipFuncAttributeMaxDynamicSharedMemorySize, SMEM_BYTES);

    prep_w_kernel<<<128, 256, 0, stream>>>(w, wsW);
    prep_const_kernel<<<1, 128, 0, stream>>>(bias, wsc);

    dim3 grid(5, 17, 32);   // q-tiles, p-tiles, n
    conv_main_kernel<<<grid, 256, SMEM_BYTES, stream>>>(x, bias, wsW, wsc, out);
}